// Round 3
// baseline (716.770 us; speedup 1.0000x reference)
//
#include <hip/hip_runtime.h>
#include <hip/hip_bf16.h>

typedef __hip_bfloat16 bf16;
typedef short short8 __attribute__((ext_vector_type(8)));
typedef float f32x4 __attribute__((ext_vector_type(4)));

#define S_LEN 2048
#define NHEADS 16
#define NKVH 4
#define HDIM 128
#define QKVN 5120
#define EPS_F 1e-6f
#define NEG_INF -1e30f
// SCALE * log2(e): attention scores computed in base-2 domain
#define QSCALE 0.12751744f
// |score*log2e| <= sqrt(128)*sqrt(128)*SCALE*log2e = 16.33 -> fixed softmax max
#define FIXED_M 17.0f

#define KT 64
#define PSTR 72

__device__ __forceinline__ void async16(const bf16* g, bf16* l) {
  __builtin_amdgcn_global_load_lds(
      (const __attribute__((address_space(1))) void*)g,
      (__attribute__((address_space(3))) void*)l, 16, 0, 0);
}

__device__ __forceinline__ f32x4 mfma_bf16(short8 a, short8 b, f32x4 c) {
  return __builtin_amdgcn_mfma_f32_16x16x32_bf16(a, b, c, 0, 0, 0);
}

__device__ __forceinline__ float bfbits_to_f(short s) {
  unsigned u = ((unsigned)(unsigned short)s) << 16;
  return __uint_as_float(u);
}
__device__ __forceinline__ short f_to_bfbits(float f) {
  __hip_bfloat16 h = __float2bfloat16(f);
  return *reinterpret_cast<short*>(&h);
}

__device__ __forceinline__ void store_c(float* p, float v) { *p = v; }
__device__ __forceinline__ void store_c(bf16* p, float v) { *p = __float2bfloat16(v); }

// ---------------- cast f32 -> bf16 ----------------
__global__ __launch_bounds__(256) void cast_kernel(const float* __restrict__ in,
                                                   bf16* __restrict__ out, int n) {
  int i = (blockIdx.x * 256 + threadIdx.x) * 4;
  if (i + 3 < n) {
    float4 v = *(const float4*)(in + i);
    __hip_bfloat162 p0, p1;
    p0.x = __float2bfloat16(v.x); p0.y = __float2bfloat16(v.y);
    p1.x = __float2bfloat16(v.z); p1.y = __float2bfloat16(v.w);
    *(__hip_bfloat162*)(out + i) = p0;
    *(__hip_bfloat162*)(out + i + 2) = p1;
  }
}

// ---------------- tiled transpose + cast: in (H,N) f32 -> out (N,H) bf16 ----------------
__global__ __launch_bounds__(256) void transpose_cast(const float* __restrict__ in,
                                                      bf16* __restrict__ out, int H, int N,
                                                      long inBS, long outBS) {
  __shared__ float tile[32][33];
  const float* ip = in + (long)blockIdx.z * inBS;
  bf16* op = out + (long)blockIdx.z * outBS;
  int n0 = blockIdx.x * 32, h0 = blockIdx.y * 32;
  int tx = threadIdx.x, ty = threadIdx.y;
#pragma unroll
  for (int i = 0; i < 4; i++)
    tile[ty + i * 8][tx] = ip[(long)(h0 + ty + i * 8) * N + n0 + tx];
  __syncthreads();
#pragma unroll
  for (int i = 0; i < 4; i++)
    op[(long)(n0 + ty + i * 8) * H + h0 + tx] = __float2bfloat16(tile[tx][ty + i * 8]);
}

// ---------------- bt-form bf16 GEMM (m97 structure): C[m][n] = sum_k A[m][k]*BT[n][k] ----------------
template <typename CT>
__global__ __launch_bounds__(256) void gemm_bt(const bf16* __restrict__ A,
                                               const bf16* __restrict__ BT,
                                               CT* __restrict__ C, int K, int ldc) {
  __shared__ bf16 As[128 * 32];
  __shared__ bf16 Bs[128 * 32];
  const int t = threadIdx.x;
  const int wid = t >> 6, lane = t & 63;
  const int quad = lane >> 4, l16 = lane & 15;
  const int wm = (wid & 1) * 64, wn = (wid >> 1) * 64;
  const long m0 = (long)blockIdx.x * 128;
  const long n0 = (long)blockIdx.y * 128;

  const int srow = t >> 2;
  const int scol = (t & 3) * 8;
  const bf16* Ag0 = A + (m0 + srow) * K + scol;
  const bf16* Ag1 = A + (m0 + srow + 64) * K + scol;
  const bf16* Bg0 = BT + (n0 + srow) * K + scol;
  const bf16* Bg1 = BT + (n0 + srow + 64) * K + scol;
  bf16* la0 = As + t * 8;
  bf16* la1 = As + 2048 + t * 8;
  bf16* lb0 = Bs + t * 8;
  bf16* lb1 = Bs + 2048 + t * 8;

  f32x4 acc[4][4] = {};

  for (int k0 = 0; k0 < K; k0 += 32) {
    __syncthreads();
    async16(Ag0 + k0, la0);
    async16(Ag1 + k0, la1);
    async16(Bg0 + k0, lb0);
    async16(Bg1 + k0, lb1);
    __syncthreads();
    short8 af[4], bfr[4];
#pragma unroll
    for (int i = 0; i < 4; i++) {
      af[i] = *(const short8*)(As + (wm + i * 16 + l16) * 32 + quad * 8);
      bfr[i] = *(const short8*)(Bs + (wn + i * 16 + l16) * 32 + quad * 8);
    }
#pragma unroll
    for (int mi = 0; mi < 4; mi++)
#pragma unroll
      for (int ni = 0; ni < 4; ni++)
        acc[mi][ni] = mfma_bf16(af[mi], bfr[ni], acc[mi][ni]);
  }

#pragma unroll
  for (int mi = 0; mi < 4; mi++)
#pragma unroll
    for (int ni = 0; ni < 4; ni++)
#pragma unroll
      for (int r = 0; r < 4; r++) {
        long row = m0 + wm + mi * 16 + quad * 4 + r;
        long col = n0 + wn + ni * 16 + l16;
        store_c(C + row * ldc + col, acc[mi][ni][r]);
      }
}

// ---------------- QKV post: rmsnorm + rope + cache writes ----------------
__global__ __launch_bounds__(256) void qkv_post(
    const bf16* __restrict__ qkv, const float* __restrict__ qw,
    const float* __restrict__ kw, const float* __restrict__ rcos,
    const float* __restrict__ rsin, bf16* __restrict__ Q, bf16* __restrict__ Kb,
    float* __restrict__ kcache, float* __restrict__ vcache) {
  const int bs = blockIdx.x;
  const int b = bs >> 11;
  const int s = bs & 2047;
  const int t = threadIdx.x, wid = t >> 6, lane = t & 63;
  const int d0 = lane * 2;
  const bf16* row = qkv + (long)bs * QKVN;
  float cs = 0.f, sn = 0.f;
  if (lane < 16) {
    cs = rcos[s * 16 + lane];
    sn = rsin[s * 16 + lane];
  }
  for (int seg = wid; seg < 24; seg += 4) {
    if (seg < 16) {
      int h = seg;
      __hip_bfloat162 xr = *(const __hip_bfloat162*)(row + h * 256 + d0);
      float x0 = __bfloat162float(xr.x), x1 = __bfloat162float(xr.y);
      float ss = x0 * x0 + x1 * x1;
      for (int o = 32; o; o >>= 1) ss += __shfl_xor(ss, o, 64);
      float rn = rsqrtf(ss * (1.0f / 128.0f) + EPS_F);
      float y0 = x0 * rn * (1.0f + qw[d0]);
      float y1 = x1 * rn * (1.0f + qw[d0 + 1]);
      if (lane < 16) {
        float t0 = y0 * cs - y1 * sn;
        y1 = y1 * cs + y0 * sn;
        y0 = t0;
      }
      y0 *= QSCALE;  // fold softmax scale * log2(e) into Q
      y1 *= QSCALE;
      __hip_bfloat162 o2;
      o2.x = __float2bfloat16(y0); o2.y = __float2bfloat16(y1);
      *(__hip_bfloat162*)(Q + ((long)(b * NHEADS + h) * S_LEN + s) * HDIM + d0) = o2;
    } else if (seg < 20) {
      int j = seg - 16;
      __hip_bfloat162 xr = *(const __hip_bfloat162*)(row + 4096 + j * 128 + d0);
      float x0 = __bfloat162float(xr.x), x1 = __bfloat162float(xr.y);
      float ss = x0 * x0 + x1 * x1;
      for (int o = 32; o; o >>= 1) ss += __shfl_xor(ss, o, 64);
      float rn = rsqrtf(ss * (1.0f / 128.0f) + EPS_F);
      float y0 = x0 * rn * (1.0f + kw[d0]);
      float y1 = x1 * rn * (1.0f + kw[d0 + 1]);
      if (lane < 16) {
        float t0 = y0 * cs - y1 * sn;
        y1 = y1 * cs + y0 * sn;
        y0 = t0;
      }
      long idx = ((long)(b * NKVH + j) * S_LEN + s) * HDIM + d0;
      __hip_bfloat162 o2;
      o2.x = __float2bfloat16(y0); o2.y = __float2bfloat16(y1);
      *(__hip_bfloat162*)(Kb + idx) = o2;
      float2 f2; f2.x = y0; f2.y = y1;
      *(float2*)(kcache + idx) = f2;
    } else {
      int j = seg - 20;
      __hip_bfloat162 xr = *(const __hip_bfloat162*)(row + 4608 + j * 128 + d0);
      float2 f2;
      f2.x = __bfloat162float(xr.x); f2.y = __bfloat162float(xr.y);
      *(float2*)(vcache + ((long)(b * NKVH + j) * S_LEN + s) * HDIM + d0) = f2;
    }
  }
}

// ---------------- flash attention (causal, GQA) + fused sigmoid gate ----------------
// Q-tile 128 (4 waves x 32 rows), K-tile 64, XOR-swizzled K/VT tiles (conflict-free),
// per-wave padded P slab (no P barrier). FIXED-MAX softmax: scores (base-2, Q
// pre-scaled) are bounded by 16.33, so exp2(s - 17) needs no running max, no
// alpha rescale, no per-tile shuffles; row-sum reduced once in epilogue.
__global__ __launch_bounds__(256, 3) void flash_attn(
    const bf16* __restrict__ Q, const bf16* __restrict__ Kb,
    const bf16* __restrict__ VT, const bf16* __restrict__ qkv,
    bf16* __restrict__ Aout) {
  __shared__ bf16 Ks[KT * 128];    // [key_row][chunk^row&15] 16B chunks
  __shared__ bf16 VTs[128 * KT];   // [d_row][chunk^row&7]
  __shared__ bf16 Ps[4 * 32 * PSTR];
  const int qt = blockIdx.x;       // qt fastest-varying (L2-friendly, round-1 order)
  const int h = blockIdx.y;
  const int b = blockIdx.z;
  const int kvh = h >> 2;
  const int t = threadIdx.x, wid = t >> 6, lane = t & 63;
  const int quad = lane >> 4, l16 = lane & 15;
  const int qm0 = qt * 128;

  const bf16* Qb = Q + ((long)(b * NHEADS + h) * S_LEN + qm0) * HDIM;
  short8 qf[2][4];
#pragma unroll
  for (int mi = 0; mi < 2; mi++)
#pragma unroll
    for (int kc = 0; kc < 4; kc++)
      qf[mi][kc] = *(const short8*)(Qb + (wid * 32 + mi * 16 + l16) * HDIM + kc * 32 + quad * 8);

  f32x4 oacc[2][8] = {};
  float lrun[2][4] = {};  // per-lane partial row sums

  const bf16* Kbase = Kb + (long)(b * NKVH + kvh) * S_LEN * HDIM;
  const bf16* VTbase = VT + (long)(b * NKVH + kvh) * HDIM * S_LEN;
  bf16* Pw = Ps + wid * (32 * PSTR);

  const int nkt = 2 * qt + 2;
  for (int kt = 0; kt < nkt; kt++) {
    const int kn0 = kt * KT;
    __syncthreads();
#pragma unroll
    for (int i = 0; i < 4; i++) {
      int ci = i * 256 + t;
      int kr = ci >> 4;
      int kc8 = ((ci & 15) ^ (kr & 15)) * 8;
      async16(Kbase + (long)(kn0 + kr) * HDIM + kc8, Ks + ci * 8);
      int vr = ci >> 3;
      int vc8 = ((ci & 7) ^ (vr & 7)) * 8;
      async16(VTbase + (long)vr * S_LEN + kn0 + vc8, VTs + ci * 8);
    }
    __syncthreads();

    // S = Q @ K^T (swizzled reads: conflict-free)
    f32x4 sacc[2][4] = {};
#pragma unroll
    for (int kc = 0; kc < 4; kc++) {
      short8 bfr[4];
#pragma unroll
      for (int ni = 0; ni < 4; ni++)
        bfr[ni] = *(const short8*)(Ks + (ni * 16 + l16) * 128 + (((kc * 4 + quad) ^ l16) << 3));
#pragma unroll
      for (int ni = 0; ni < 4; ni++)
#pragma unroll
        for (int mi = 0; mi < 2; mi++)
          sacc[mi][ni] = mfma_bf16(qf[mi][kc], bfr[ni], sacc[mi][ni]);
    }

    // fixed-max softmax: p = exp2(s - 17); accumulate per-lane partial sums
    const bool diag = (kt >= 2 * qt);
#pragma unroll
    for (int mi = 0; mi < 2; mi++)
#pragma unroll
      for (int r = 0; r < 4; r++) {
        const int rloc = wid * 32 + mi * 16 + quad * 4 + r;
        if (diag) {
#pragma unroll
          for (int ni = 0; ni < 4; ni++)
            if (kn0 + ni * 16 + l16 > qm0 + rloc) sacc[mi][ni][r] = NEG_INF;
        }
        float rsum = lrun[mi][r];
#pragma unroll
        for (int ni = 0; ni < 4; ni++) {
          float p = exp2f(sacc[mi][ni][r] - FIXED_M);
          sacc[mi][ni][r] = p;
          rsum += p;
        }
        lrun[mi][r] = rsum;
      }

    // P -> own LDS slab (padded stride; no barrier needed)
#pragma unroll
    for (int mi = 0; mi < 2; mi++)
#pragma unroll
      for (int ni = 0; ni < 4; ni++)
#pragma unroll
        for (int r = 0; r < 4; r++)
          Pw[(mi * 16 + quad * 4 + r) * PSTR + ni * 16 + l16] =
              __float2bfloat16(sacc[mi][ni][r]);

    // O += P @ V
#pragma unroll
    for (int kc = 0; kc < 2; kc++) {
      short8 pf[2];
#pragma unroll
      for (int mi = 0; mi < 2; mi++)
        pf[mi] = *(const short8*)(Pw + (mi * 16 + l16) * PSTR + kc * 32 + quad * 8);
#pragma unroll
      for (int ni = 0; ni < 8; ni++) {
        short8 vf = *(const short8*)(VTs + (ni * 16 + l16) * KT +
                                     (((kc * 4 + quad) ^ (l16 & 7)) << 3));
#pragma unroll
        for (int mi = 0; mi < 2; mi++)
          oacc[mi][ni] = mfma_bf16(pf[mi], vf, oacc[mi][ni]);
      }
    }
  }

  // epilogue: reduce row sums once, repack O via own P slab, gate, coalesced store
  float inv[2][4];
#pragma unroll
  for (int mi = 0; mi < 2; mi++)
#pragma unroll
    for (int r = 0; r < 4; r++) {
      float s = lrun[mi][r];
#pragma unroll
      for (int o = 1; o < 16; o <<= 1) s += __shfl_xor(s, o, 64);
      inv[mi][r] = 1.0f / s;
    }

#pragma unroll
  for (int h2 = 0; h2 < 2; h2++) {
    // write normalized O into own slab (cols h2*64..h2*64+63)
#pragma unroll
    for (int mi = 0; mi < 2; mi++)
#pragma unroll
      for (int nj = 0; nj < 4; nj++)
#pragma unroll
        for (int r = 0; r < 4; r++)
          Pw[(mi * 16 + quad * 4 + r) * PSTR + nj * 16 + l16] =
              __float2bfloat16(oacc[mi][h2 * 4 + nj][r] * inv[mi][r]);
    // readback rows, apply sigmoid gate (16B loads), 16B coalesced stores
#pragma unroll
    for (int i = 0; i < 4; i++) {
      const int lrow = i * 8 + (lane >> 3);
      const int coff = (lane & 7) * 8;
      short8 o8 = *(const short8*)(Pw + lrow * PSTR + coff);
      const long srow = qm0 + wid * 32 + lrow;
      const bf16* gp = qkv + ((long)b * S_LEN + srow) * QKVN + h * 256 + 128 + h2 * 64 + coff;
      short8 g8 = *(const short8*)gp;
      short8 res;
#pragma unroll
      for (int e = 0; e < 8; e++) {
        float ov = bfbits_to_f(o8[e]);
        float gv = bfbits_to_f(g8[e]);
        res[e] = f_to_bfbits(ov / (1.0f + __expf(-gv)));
      }
      *(short8*)(Aout + ((long)b * S_LEN + srow) * 2048 + h * 128 + h2 * 64 + coff) = res;
    }
  }
}

extern "C" void kernel_launch(void* const* d_in, const int* in_sizes, int n_in,
                              void* d_out, int out_size, void* d_ws, size_t ws_size,
                              hipStream_t stream) {
  const float* hs = (const float*)d_in[0];
  const float* wq = (const float*)d_in[1];
  const float* wk = (const float*)d_in[2];
  const float* wv = (const float*)d_in[3];
  const float* wo = (const float*)d_in[4];
  const float* qnw = (const float*)d_in[5];
  const float* knw = (const float*)d_in[6];
  const float* rcos = (const float*)d_in[7];
  const float* rsin = (const float*)d_in[8];

  float* out = (float*)d_out;                 // (2,2048,2048)
  float* kcache = out + 8388608;              // (2,4,2048,128)
  float* vcache = out + 10485760;             // (2,4,2048,128)

  char* ws = (char*)d_ws;
  bf16* Xb    = (bf16*)(ws);                  // (4096,2048)
  bf16* WqkvT = (bf16*)(ws + 16777216L);      // (5120,2048)
  bf16* WoT   = (bf16*)(ws + 37748736L);      // (2048,2048)
  bf16* QKV   = (bf16*)(ws + 46137344L);      // (4096,5120)
  bf16* Qb    = (bf16*)(ws + 88080384L);      // (2,16,2048,128)
  bf16* Kbq   = (bf16*)(ws + 104857600L);     // (2,4,2048,128)
  bf16* VTb   = (bf16*)(ws + 109051904L);     // (2,4,128,2048)
  bf16* Aout  = (bf16*)(ws + 113246208L);     // (4096,2048)

  cast_kernel<<<8192, 256, 0, stream>>>(hs, Xb, 8388608);
  transpose_cast<<<dim3(128, 64, 1), dim3(32, 8), 0, stream>>>(wq, WqkvT, 2048, 4096, 0, 0);
  transpose_cast<<<dim3(16, 64, 1), dim3(32, 8), 0, stream>>>(wk, WqkvT + 4096L * 2048, 2048, 512, 0, 0);
  transpose_cast<<<dim3(16, 64, 1), dim3(32, 8), 0, stream>>>(wv, WqkvT + 4608L * 2048, 2048, 512, 0, 0);
  transpose_cast<<<dim3(64, 64, 1), dim3(32, 8), 0, stream>>>(wo, WoT, 2048, 2048, 0, 0);

  gemm_bt<bf16><<<dim3(32, 40), 256, 0, stream>>>(Xb, WqkvT, QKV, 2048, 5120);

  qkv_post<<<4096, 256, 0, stream>>>(QKV, qnw, knw, rcos, rsin, Qb, Kbq, kcache, vcache);

  // V^T (per (b,kv): (2048,128) f32 -> (128,2048) bf16)
  transpose_cast<<<dim3(4, 64, 8), dim3(32, 8), 0, stream>>>(vcache, VTb, 2048, 128,
                                                             2048L * 128, 2048L * 128);

  flash_attn<<<dim3(16, 16, 2), 256, 0, stream>>>(Qb, Kbq, VTb, QKV, Aout);

  gemm_bt<float><<<dim3(32, 16), 256, 0, stream>>>(Aout, WoT, out, 2048, 2048);
}

// Round 4
// 644.850 us; speedup vs baseline: 1.1115x; 1.1115x over previous
//
#include <hip/hip_runtime.h>
#include <hip/hip_bf16.h>

typedef __hip_bfloat16 bf16;
typedef short short8 __attribute__((ext_vector_type(8)));
typedef float f32x4 __attribute__((ext_vector_type(4)));

#define S_LEN 2048
#define NHEADS 16
#define NKVH 4
#define HDIM 128
#define QKVN 5120
#define EPS_F 1e-6f
#define NEG_INF -1e30f
// SCALE * log2(e): attention scores computed in base-2 domain
#define QSCALE 0.12751744f
// |score*log2e| <= sqrt(128)*sqrt(128)*SCALE*log2e = 16.33 -> fixed softmax max
#define FIXED_M 17.0f

#define KT 64
#define PSTR 72

__device__ __forceinline__ void async16(const bf16* g, bf16* l) {
  __builtin_amdgcn_global_load_lds(
      (const __attribute__((address_space(1))) void*)g,
      (__attribute__((address_space(3))) void*)l, 16, 0, 0);
}

__device__ __forceinline__ f32x4 mfma_bf16(short8 a, short8 b, f32x4 c) {
  return __builtin_amdgcn_mfma_f32_16x16x32_bf16(a, b, c, 0, 0, 0);
}

__device__ __forceinline__ float bfbits_to_f(short s) {
  unsigned u = ((unsigned)(unsigned short)s) << 16;
  return __uint_as_float(u);
}
__device__ __forceinline__ short f_to_bfbits(float f) {
  __hip_bfloat16 h = __float2bfloat16(f);
  return *reinterpret_cast<short*>(&h);
}

__device__ __forceinline__ void store_c(float* p, float v) { *p = v; }
__device__ __forceinline__ void store_c(bf16* p, float v) { *p = __float2bfloat16(v); }

// ---------------- cast f32 -> bf16 ----------------
__global__ __launch_bounds__(256) void cast_kernel(const float* __restrict__ in,
                                                   bf16* __restrict__ out, int n) {
  int i = (blockIdx.x * 256 + threadIdx.x) * 4;
  if (i + 3 < n) {
    float4 v = *(const float4*)(in + i);
    __hip_bfloat162 p0, p1;
    p0.x = __float2bfloat16(v.x); p0.y = __float2bfloat16(v.y);
    p1.x = __float2bfloat16(v.z); p1.y = __float2bfloat16(v.w);
    *(__hip_bfloat162*)(out + i) = p0;
    *(__hip_bfloat162*)(out + i + 2) = p1;
  }
}

// ---------------- tiled transpose + cast: in (H,N) f32 -> out (N,H) bf16 ----------------
__global__ __launch_bounds__(256) void transpose_cast(const float* __restrict__ in,
                                                      bf16* __restrict__ out, int H, int N,
                                                      long inBS, long outBS) {
  __shared__ float tile[32][33];
  const float* ip = in + (long)blockIdx.z * inBS;
  bf16* op = out + (long)blockIdx.z * outBS;
  int n0 = blockIdx.x * 32, h0 = blockIdx.y * 32;
  int tx = threadIdx.x, ty = threadIdx.y;
#pragma unroll
  for (int i = 0; i < 4; i++)
    tile[ty + i * 8][tx] = ip[(long)(h0 + ty + i * 8) * N + n0 + tx];
  __syncthreads();
#pragma unroll
  for (int i = 0; i < 4; i++)
    op[(long)(n0 + ty + i * 8) * H + h0 + tx] = __float2bfloat16(tile[tx][ty + i * 8]);
}

// ---------------- bt-form bf16 GEMM (m97 structure): C[m][n] = sum_k A[m][k]*BT[n][k] ----------------
template <typename CT>
__global__ __launch_bounds__(256) void gemm_bt(const bf16* __restrict__ A,
                                               const bf16* __restrict__ BT,
                                               CT* __restrict__ C, int K, int ldc) {
  __shared__ bf16 As[128 * 32];
  __shared__ bf16 Bs[128 * 32];
  const int t = threadIdx.x;
  const int wid = t >> 6, lane = t & 63;
  const int quad = lane >> 4, l16 = lane & 15;
  const int wm = (wid & 1) * 64, wn = (wid >> 1) * 64;
  const long m0 = (long)blockIdx.x * 128;
  const long n0 = (long)blockIdx.y * 128;

  const int srow = t >> 2;
  const int scol = (t & 3) * 8;
  const bf16* Ag0 = A + (m0 + srow) * K + scol;
  const bf16* Ag1 = A + (m0 + srow + 64) * K + scol;
  const bf16* Bg0 = BT + (n0 + srow) * K + scol;
  const bf16* Bg1 = BT + (n0 + srow + 64) * K + scol;
  bf16* la0 = As + t * 8;
  bf16* la1 = As + 2048 + t * 8;
  bf16* lb0 = Bs + t * 8;
  bf16* lb1 = Bs + 2048 + t * 8;

  f32x4 acc[4][4] = {};

  for (int k0 = 0; k0 < K; k0 += 32) {
    __syncthreads();
    async16(Ag0 + k0, la0);
    async16(Ag1 + k0, la1);
    async16(Bg0 + k0, lb0);
    async16(Bg1 + k0, lb1);
    __syncthreads();
    short8 af[4], bfr[4];
#pragma unroll
    for (int i = 0; i < 4; i++) {
      af[i] = *(const short8*)(As + (wm + i * 16 + l16) * 32 + quad * 8);
      bfr[i] = *(const short8*)(Bs + (wn + i * 16 + l16) * 32 + quad * 8);
    }
#pragma unroll
    for (int mi = 0; mi < 4; mi++)
#pragma unroll
      for (int ni = 0; ni < 4; ni++)
        acc[mi][ni] = mfma_bf16(af[mi], bfr[ni], acc[mi][ni]);
  }

#pragma unroll
  for (int mi = 0; mi < 4; mi++)
#pragma unroll
    for (int ni = 0; ni < 4; ni++)
#pragma unroll
      for (int r = 0; r < 4; r++) {
        long row = m0 + wm + mi * 16 + quad * 4 + r;
        long col = n0 + wn + ni * 16 + l16;
        store_c(C + row * ldc + col, acc[mi][ni][r]);
      }
}

// ---------------- QKV post: rmsnorm + rope + cache writes ----------------
__global__ __launch_bounds__(256) void qkv_post(
    const bf16* __restrict__ qkv, const float* __restrict__ qw,
    const float* __restrict__ kw, const float* __restrict__ rcos,
    const float* __restrict__ rsin, bf16* __restrict__ Q, bf16* __restrict__ Kb,
    float* __restrict__ kcache, float* __restrict__ vcache) {
  const int bs = blockIdx.x;
  const int b = bs >> 11;
  const int s = bs & 2047;
  const int t = threadIdx.x, wid = t >> 6, lane = t & 63;
  const int d0 = lane * 2;
  const bf16* row = qkv + (long)bs * QKVN;
  float cs = 0.f, sn = 0.f;
  if (lane < 16) {
    cs = rcos[s * 16 + lane];
    sn = rsin[s * 16 + lane];
  }
  for (int seg = wid; seg < 24; seg += 4) {
    if (seg < 16) {
      int h = seg;
      __hip_bfloat162 xr = *(const __hip_bfloat162*)(row + h * 256 + d0);
      float x0 = __bfloat162float(xr.x), x1 = __bfloat162float(xr.y);
      float ss = x0 * x0 + x1 * x1;
      for (int o = 32; o; o >>= 1) ss += __shfl_xor(ss, o, 64);
      float rn = rsqrtf(ss * (1.0f / 128.0f) + EPS_F);
      float y0 = x0 * rn * (1.0f + qw[d0]);
      float y1 = x1 * rn * (1.0f + qw[d0 + 1]);
      if (lane < 16) {
        float t0 = y0 * cs - y1 * sn;
        y1 = y1 * cs + y0 * sn;
        y0 = t0;
      }
      y0 *= QSCALE;  // fold softmax scale * log2(e) into Q
      y1 *= QSCALE;
      __hip_bfloat162 o2;
      o2.x = __float2bfloat16(y0); o2.y = __float2bfloat16(y1);
      *(__hip_bfloat162*)(Q + ((long)(b * NHEADS + h) * S_LEN + s) * HDIM + d0) = o2;
    } else if (seg < 20) {
      int j = seg - 16;
      __hip_bfloat162 xr = *(const __hip_bfloat162*)(row + 4096 + j * 128 + d0);
      float x0 = __bfloat162float(xr.x), x1 = __bfloat162float(xr.y);
      float ss = x0 * x0 + x1 * x1;
      for (int o = 32; o; o >>= 1) ss += __shfl_xor(ss, o, 64);
      float rn = rsqrtf(ss * (1.0f / 128.0f) + EPS_F);
      float y0 = x0 * rn * (1.0f + kw[d0]);
      float y1 = x1 * rn * (1.0f + kw[d0 + 1]);
      if (lane < 16) {
        float t0 = y0 * cs - y1 * sn;
        y1 = y1 * cs + y0 * sn;
        y0 = t0;
      }
      long idx = ((long)(b * NKVH + j) * S_LEN + s) * HDIM + d0;
      __hip_bfloat162 o2;
      o2.x = __float2bfloat16(y0); o2.y = __float2bfloat16(y1);
      *(__hip_bfloat162*)(Kb + idx) = o2;
      float2 f2; f2.x = y0; f2.y = y1;
      *(float2*)(kcache + idx) = f2;
    } else {
      int j = seg - 20;
      __hip_bfloat162 xr = *(const __hip_bfloat162*)(row + 4608 + j * 128 + d0);
      float2 f2;
      f2.x = __bfloat162float(xr.x); f2.y = __bfloat162float(xr.y);
      *(float2*)(vcache + ((long)(b * NKVH + j) * S_LEN + s) * HDIM + d0) = f2;
    }
  }
}

// ---------------- flash attention (causal, GQA) + fused sigmoid gate ----------------
// Q-tile 128 (4 waves x 32 rows), K-tile 64, XOR-swizzled K/VT tiles (conflict-free),
// per-wave padded P slab (no P barrier), fixed-max base-2 softmax (no running max).
// Grid is XCD-PINNED: bid%8 selects the (b,kvh) group, so all 64 blocks sharing one
// 1 MB K/V stream land on one XCD -> K/V lives in that XCD's 4 MB L2. Within an XCD,
// long-qt blocks dispatch first and slot j pairs with j+32 s.t. qt sums are constant
// (uniform 34 tile-iters per CU).
__global__ __launch_bounds__(256, 3) void flash_attn(
    const bf16* __restrict__ Q, const bf16* __restrict__ Kb,
    const bf16* __restrict__ VT, const bf16* __restrict__ qkv,
    bf16* __restrict__ Aout) {
  __shared__ bf16 Ks[KT * 128];    // [key_row][chunk^row&15] 16B chunks
  __shared__ bf16 VTs[128 * KT];   // [d_row][chunk^row&7]
  __shared__ bf16 Ps[4 * 32 * PSTR];
  const int bid = blockIdx.x;
  const int group = bid & 7;       // XCD pin: all same-group blocks share K/V
  const int b = group >> 2;
  const int kvh = group & 3;
  const int j = bid >> 3;          // 0..63 within group
  const int h = kvh * 4 + (j & 3);
  const int qt = (j < 32) ? (15 - (j >> 2)) : ((j - 32) >> 2);
  const int t = threadIdx.x, wid = t >> 6, lane = t & 63;
  const int quad = lane >> 4, l16 = lane & 15;
  const int qm0 = qt * 128;

  const bf16* Qb = Q + ((long)(b * NHEADS + h) * S_LEN + qm0) * HDIM;
  short8 qf[2][4];
#pragma unroll
  for (int mi = 0; mi < 2; mi++)
#pragma unroll
    for (int kc = 0; kc < 4; kc++)
      qf[mi][kc] = *(const short8*)(Qb + (wid * 32 + mi * 16 + l16) * HDIM + kc * 32 + quad * 8);

  f32x4 oacc[2][8] = {};
  float lrun[2][4] = {};  // per-lane partial row sums

  const bf16* Kbase = Kb + (long)(b * NKVH + kvh) * S_LEN * HDIM;
  const bf16* VTbase = VT + (long)(b * NKVH + kvh) * HDIM * S_LEN;
  bf16* Pw = Ps + wid * (32 * PSTR);

  const int nkt = 2 * qt + 2;
  for (int kt = 0; kt < nkt; kt++) {
    const int kn0 = kt * KT;
    __syncthreads();
#pragma unroll
    for (int i = 0; i < 4; i++) {
      int ci = i * 256 + t;
      int kr = ci >> 4;
      int kc8 = ((ci & 15) ^ (kr & 15)) * 8;
      async16(Kbase + (long)(kn0 + kr) * HDIM + kc8, Ks + ci * 8);
      int vr = ci >> 3;
      int vc8 = ((ci & 7) ^ (vr & 7)) * 8;
      async16(VTbase + (long)vr * S_LEN + kn0 + vc8, VTs + ci * 8);
    }
    __syncthreads();

    // S = Q @ K^T (swizzled reads: conflict-free)
    f32x4 sacc[2][4] = {};
#pragma unroll
    for (int kc = 0; kc < 4; kc++) {
      short8 bfr[4];
#pragma unroll
      for (int ni = 0; ni < 4; ni++)
        bfr[ni] = *(const short8*)(Ks + (ni * 16 + l16) * 128 + (((kc * 4 + quad) ^ l16) << 3));
#pragma unroll
      for (int ni = 0; ni < 4; ni++)
#pragma unroll
        for (int mi = 0; mi < 2; mi++)
          sacc[mi][ni] = mfma_bf16(qf[mi][kc], bfr[ni], sacc[mi][ni]);
    }

    // fixed-max softmax: p = exp2(s - 17); accumulate per-lane partial sums
    const bool diag = (kt >= 2 * qt);
#pragma unroll
    for (int mi = 0; mi < 2; mi++)
#pragma unroll
      for (int r = 0; r < 4; r++) {
        const int rloc = wid * 32 + mi * 16 + quad * 4 + r;
        if (diag) {
#pragma unroll
          for (int ni = 0; ni < 4; ni++)
            if (kn0 + ni * 16 + l16 > qm0 + rloc) sacc[mi][ni][r] = NEG_INF;
        }
        float rsum = lrun[mi][r];
#pragma unroll
        for (int ni = 0; ni < 4; ni++) {
          float p = exp2f(sacc[mi][ni][r] - FIXED_M);
          sacc[mi][ni][r] = p;
          rsum += p;
        }
        lrun[mi][r] = rsum;
      }

    // P -> own LDS slab (padded stride; no barrier needed)
#pragma unroll
    for (int mi = 0; mi < 2; mi++)
#pragma unroll
      for (int ni = 0; ni < 4; ni++)
#pragma unroll
        for (int r = 0; r < 4; r++)
          Pw[(mi * 16 + quad * 4 + r) * PSTR + ni * 16 + l16] =
              __float2bfloat16(sacc[mi][ni][r]);

    // O += P @ V
#pragma unroll
    for (int kc = 0; kc < 2; kc++) {
      short8 pf[2];
#pragma unroll
      for (int mi = 0; mi < 2; mi++)
        pf[mi] = *(const short8*)(Pw + (mi * 16 + l16) * PSTR + kc * 32 + quad * 8);
#pragma unroll
      for (int ni = 0; ni < 8; ni++) {
        short8 vf = *(const short8*)(VTs + (ni * 16 + l16) * KT +
                                     (((kc * 4 + quad) ^ (l16 & 7)) << 3));
#pragma unroll
        for (int mi = 0; mi < 2; mi++)
          oacc[mi][ni] = mfma_bf16(pf[mi], vf, oacc[mi][ni]);
      }
    }
  }

  // epilogue: reduce row sums once, repack O via own P slab, gate, coalesced store
  float inv[2][4];
#pragma unroll
  for (int mi = 0; mi < 2; mi++)
#pragma unroll
    for (int r = 0; r < 4; r++) {
      float s = lrun[mi][r];
#pragma unroll
      for (int o = 1; o < 16; o <<= 1) s += __shfl_xor(s, o, 64);
      inv[mi][r] = 1.0f / s;
    }

#pragma unroll
  for (int h2 = 0; h2 < 2; h2++) {
    // write normalized O into own slab (cols h2*64..h2*64+63)
#pragma unroll
    for (int mi = 0; mi < 2; mi++)
#pragma unroll
      for (int nj = 0; nj < 4; nj++)
#pragma unroll
        for (int r = 0; r < 4; r++)
          Pw[(mi * 16 + quad * 4 + r) * PSTR + nj * 16 + l16] =
              __float2bfloat16(oacc[mi][h2 * 4 + nj][r] * inv[mi][r]);
    // readback rows, apply sigmoid gate (16B loads), 16B coalesced stores
#pragma unroll
    for (int i = 0; i < 4; i++) {
      const int lrow = i * 8 + (lane >> 3);
      const int coff = (lane & 7) * 8;
      short8 o8 = *(const short8*)(Pw + lrow * PSTR + coff);
      const long srow = qm0 + wid * 32 + lrow;
      const bf16* gp = qkv + ((long)b * S_LEN + srow) * QKVN + h * 256 + 128 + h2 * 64 + coff;
      short8 g8 = *(const short8*)gp;
      short8 res;
#pragma unroll
      for (int e = 0; e < 8; e++) {
        float ov = bfbits_to_f(o8[e]);
        float gv = bfbits_to_f(g8[e]);
        res[e] = f_to_bfbits(ov / (1.0f + __expf(-gv)));
      }
      *(short8*)(Aout + ((long)b * S_LEN + srow) * 2048 + h * 128 + h2 * 64 + coff) = res;
    }
  }
}

extern "C" void kernel_launch(void* const* d_in, const int* in_sizes, int n_in,
                              void* d_out, int out_size, void* d_ws, size_t ws_size,
                              hipStream_t stream) {
  const float* hs = (const float*)d_in[0];
  const float* wq = (const float*)d_in[1];
  const float* wk = (const float*)d_in[2];
  const float* wv = (const float*)d_in[3];
  const float* wo = (const float*)d_in[4];
  const float* qnw = (const float*)d_in[5];
  const float* knw = (const float*)d_in[6];
  const float* rcos = (const float*)d_in[7];
  const float* rsin = (const float*)d_in[8];

  float* out = (float*)d_out;                 // (2,2048,2048)
  float* kcache = out + 8388608;              // (2,4,2048,128)
  float* vcache = out + 10485760;             // (2,4,2048,128)

  char* ws = (char*)d_ws;
  bf16* Xb    = (bf16*)(ws);                  // (4096,2048)
  bf16* WqkvT = (bf16*)(ws + 16777216L);      // (5120,2048)
  bf16* WoT   = (bf16*)(ws + 37748736L);      // (2048,2048)
  bf16* QKV   = (bf16*)(ws + 46137344L);      // (4096,5120)
  bf16* Qb    = (bf16*)(ws + 88080384L);      // (2,16,2048,128)
  bf16* Kbq   = (bf16*)(ws + 104857600L);     // (2,4,2048,128)
  bf16* VTb   = (bf16*)(ws + 109051904L);     // (2,4,128,2048)
  bf16* Aout  = (bf16*)(ws + 113246208L);     // (4096,2048)

  cast_kernel<<<8192, 256, 0, stream>>>(hs, Xb, 8388608);
  transpose_cast<<<dim3(128, 64, 1), dim3(32, 8), 0, stream>>>(wq, WqkvT, 2048, 4096, 0, 0);
  transpose_cast<<<dim3(16, 64, 1), dim3(32, 8), 0, stream>>>(wk, WqkvT + 4096L * 2048, 2048, 512, 0, 0);
  transpose_cast<<<dim3(16, 64, 1), dim3(32, 8), 0, stream>>>(wv, WqkvT + 4608L * 2048, 2048, 512, 0, 0);
  transpose_cast<<<dim3(64, 64, 1), dim3(32, 8), 0, stream>>>(wo, WoT, 2048, 2048, 0, 0);

  gemm_bt<bf16><<<dim3(32, 40), 256, 0, stream>>>(Xb, WqkvT, QKV, 2048, 5120);

  qkv_post<<<4096, 256, 0, stream>>>(QKV, qnw, knw, rcos, rsin, Qb, Kbq, kcache, vcache);

  // V^T (per (b,kv): (2048,128) f32 -> (128,2048) bf16)
  transpose_cast<<<dim3(4, 64, 8), dim3(32, 8), 0, stream>>>(vcache, VTb, 2048, 128,
                                                             2048L * 128, 2048L * 128);

  flash_attn<<<512, 256, 0, stream>>>(Qb, Kbq, VTb, QKV, Aout);

  gemm_bt<float><<<dim3(32, 16), 256, 0, stream>>>(Aout, WoT, out, 2048, 2048);
}

// Round 5
// 446.881 us; speedup vs baseline: 1.6039x; 1.4430x over previous
//
#include <hip/hip_runtime.h>
#include <hip/hip_bf16.h>

typedef __hip_bfloat16 bf16;
typedef short short8 __attribute__((ext_vector_type(8)));
typedef float f32x4 __attribute__((ext_vector_type(4)));

#define S_LEN 2048
#define NHEADS 16
#define NKVH 4
#define HDIM 128
#define QKVN 5120
#define EPS_F 1e-6f
#define NEG_INF -1e30f
// SCALE * log2(e): attention scores computed in base-2 domain
#define QSCALE 0.12751744f
// |score*log2e| <= sqrt(128)*sqrt(128)*SCALE*log2e = 16.33 -> fixed softmax max
#define FIXED_M 17.0f

#define KT 64

__device__ __forceinline__ void async16(const bf16* g, bf16* l) {
  __builtin_amdgcn_global_load_lds(
      (const __attribute__((address_space(1))) void*)g,
      (__attribute__((address_space(3))) void*)l, 16, 0, 0);
}

__device__ __forceinline__ f32x4 mfma_bf16(short8 a, short8 b, f32x4 c) {
  return __builtin_amdgcn_mfma_f32_16x16x32_bf16(a, b, c, 0, 0, 0);
}

__device__ __forceinline__ float bfbits_to_f(short s) {
  unsigned u = ((unsigned)(unsigned short)s) << 16;
  return __uint_as_float(u);
}
__device__ __forceinline__ short f_to_bfbits(float f) {
  __hip_bfloat16 h = __float2bfloat16(f);
  return *reinterpret_cast<short*>(&h);
}

__device__ __forceinline__ void store_c(float* p, float v) { *p = v; }
__device__ __forceinline__ void store_c(bf16* p, float v) { *p = __float2bfloat16(v); }

// ---------------- cast f32 -> bf16 ----------------
__global__ __launch_bounds__(256) void cast_kernel(const float* __restrict__ in,
                                                   bf16* __restrict__ out, int n) {
  int i = (blockIdx.x * 256 + threadIdx.x) * 4;
  if (i + 3 < n) {
    float4 v = *(const float4*)(in + i);
    __hip_bfloat162 p0, p1;
    p0.x = __float2bfloat16(v.x); p0.y = __float2bfloat16(v.y);
    p1.x = __float2bfloat16(v.z); p1.y = __float2bfloat16(v.w);
    *(__hip_bfloat162*)(out + i) = p0;
    *(__hip_bfloat162*)(out + i + 2) = p1;
  }
}

// ---------------- tiled transpose + cast: in (H,N) f32 -> out (N,H) bf16 ----------------
__global__ __launch_bounds__(256) void transpose_cast(const float* __restrict__ in,
                                                      bf16* __restrict__ out, int H, int N,
                                                      long inBS, long outBS) {
  __shared__ float tile[32][33];
  const float* ip = in + (long)blockIdx.z * inBS;
  bf16* op = out + (long)blockIdx.z * outBS;
  int n0 = blockIdx.x * 32, h0 = blockIdx.y * 32;
  int tx = threadIdx.x, ty = threadIdx.y;
#pragma unroll
  for (int i = 0; i < 4; i++)
    tile[ty + i * 8][tx] = ip[(long)(h0 + ty + i * 8) * N + n0 + tx];
  __syncthreads();
#pragma unroll
  for (int i = 0; i < 4; i++)
    op[(long)(n0 + ty + i * 8) * H + h0 + tx] = __float2bfloat16(tile[tx][ty + i * 8]);
}

// ---------------- bt-form bf16 GEMM (m97 structure): C[m][n] = sum_k A[m][k]*BT[n][k] ----------------
template <typename CT>
__global__ __launch_bounds__(256) void gemm_bt(const bf16* __restrict__ A,
                                               const bf16* __restrict__ BT,
                                               CT* __restrict__ C, int K, int ldc) {
  __shared__ bf16 As[128 * 32];
  __shared__ bf16 Bs[128 * 32];
  const int t = threadIdx.x;
  const int wid = t >> 6, lane = t & 63;
  const int quad = lane >> 4, l16 = lane & 15;
  const int wm = (wid & 1) * 64, wn = (wid >> 1) * 64;
  const long m0 = (long)blockIdx.x * 128;
  const long n0 = (long)blockIdx.y * 128;

  const int srow = t >> 2;
  const int scol = (t & 3) * 8;
  const bf16* Ag0 = A + (m0 + srow) * K + scol;
  const bf16* Ag1 = A + (m0 + srow + 64) * K + scol;
  const bf16* Bg0 = BT + (n0 + srow) * K + scol;
  const bf16* Bg1 = BT + (n0 + srow + 64) * K + scol;
  bf16* la0 = As + t * 8;
  bf16* la1 = As + 2048 + t * 8;
  bf16* lb0 = Bs + t * 8;
  bf16* lb1 = Bs + 2048 + t * 8;

  f32x4 acc[4][4] = {};

  for (int k0 = 0; k0 < K; k0 += 32) {
    __syncthreads();
    async16(Ag0 + k0, la0);
    async16(Ag1 + k0, la1);
    async16(Bg0 + k0, lb0);
    async16(Bg1 + k0, lb1);
    __syncthreads();
    short8 af[4], bfr[4];
#pragma unroll
    for (int i = 0; i < 4; i++) {
      af[i] = *(const short8*)(As + (wm + i * 16 + l16) * 32 + quad * 8);
      bfr[i] = *(const short8*)(Bs + (wn + i * 16 + l16) * 32 + quad * 8);
    }
#pragma unroll
    for (int mi = 0; mi < 4; mi++)
#pragma unroll
      for (int ni = 0; ni < 4; ni++)
        acc[mi][ni] = mfma_bf16(af[mi], bfr[ni], acc[mi][ni]);
  }

#pragma unroll
  for (int mi = 0; mi < 4; mi++)
#pragma unroll
    for (int ni = 0; ni < 4; ni++)
#pragma unroll
      for (int r = 0; r < 4; r++) {
        long row = m0 + wm + mi * 16 + quad * 4 + r;
        long col = n0 + wn + ni * 16 + l16;
        store_c(C + row * ldc + col, acc[mi][ni][r]);
      }
}

// ---------------- QKV post: rmsnorm + rope + cache writes ----------------
__global__ __launch_bounds__(256) void qkv_post(
    const bf16* __restrict__ qkv, const float* __restrict__ qw,
    const float* __restrict__ kw, const float* __restrict__ rcos,
    const float* __restrict__ rsin, bf16* __restrict__ Q, bf16* __restrict__ Kb,
    float* __restrict__ kcache, float* __restrict__ vcache) {
  const int bs = blockIdx.x;
  const int b = bs >> 11;
  const int s = bs & 2047;
  const int t = threadIdx.x, wid = t >> 6, lane = t & 63;
  const int d0 = lane * 2;
  const bf16* row = qkv + (long)bs * QKVN;
  float cs = 0.f, sn = 0.f;
  if (lane < 16) {
    cs = rcos[s * 16 + lane];
    sn = rsin[s * 16 + lane];
  }
  for (int seg = wid; seg < 24; seg += 4) {
    if (seg < 16) {
      int h = seg;
      __hip_bfloat162 xr = *(const __hip_bfloat162*)(row + h * 256 + d0);
      float x0 = __bfloat162float(xr.x), x1 = __bfloat162float(xr.y);
      float ss = x0 * x0 + x1 * x1;
      for (int o = 32; o; o >>= 1) ss += __shfl_xor(ss, o, 64);
      float rn = rsqrtf(ss * (1.0f / 128.0f) + EPS_F);
      float y0 = x0 * rn * (1.0f + qw[d0]);
      float y1 = x1 * rn * (1.0f + qw[d0 + 1]);
      if (lane < 16) {
        float t0 = y0 * cs - y1 * sn;
        y1 = y1 * cs + y0 * sn;
        y0 = t0;
      }
      y0 *= QSCALE;  // fold softmax scale * log2(e) into Q
      y1 *= QSCALE;
      __hip_bfloat162 o2;
      o2.x = __float2bfloat16(y0); o2.y = __float2bfloat16(y1);
      *(__hip_bfloat162*)(Q + ((long)(b * NHEADS + h) * S_LEN + s) * HDIM + d0) = o2;
    } else if (seg < 20) {
      int j = seg - 16;
      __hip_bfloat162 xr = *(const __hip_bfloat162*)(row + 4096 + j * 128 + d0);
      float x0 = __bfloat162float(xr.x), x1 = __bfloat162float(xr.y);
      float ss = x0 * x0 + x1 * x1;
      for (int o = 32; o; o >>= 1) ss += __shfl_xor(ss, o, 64);
      float rn = rsqrtf(ss * (1.0f / 128.0f) + EPS_F);
      float y0 = x0 * rn * (1.0f + kw[d0]);
      float y1 = x1 * rn * (1.0f + kw[d0 + 1]);
      if (lane < 16) {
        float t0 = y0 * cs - y1 * sn;
        y1 = y1 * cs + y0 * sn;
        y0 = t0;
      }
      long idx = ((long)(b * NKVH + j) * S_LEN + s) * HDIM + d0;
      __hip_bfloat162 o2;
      o2.x = __float2bfloat16(y0); o2.y = __float2bfloat16(y1);
      *(__hip_bfloat162*)(Kb + idx) = o2;
      float2 f2; f2.x = y0; f2.y = y1;
      *(float2*)(kcache + idx) = f2;
    } else {
      int j = seg - 20;
      __hip_bfloat162 xr = *(const __hip_bfloat162*)(row + 4608 + j * 128 + d0);
      float2 f2;
      f2.x = __bfloat162float(xr.x); f2.y = __bfloat162float(xr.y);
      *(float2*)(vcache + ((long)(b * NKVH + j) * S_LEN + s) * HDIM + d0) = f2;
    }
  }
}

// ---------------- flash attention (causal, GQA) + fused sigmoid gate ----------------
// GQA head-sharing block: 512 threads = 8 waves = 4 heads x 2 q-halves, all sharing
// ONE staged K/V tile (KT=64). This halves K/V staging traffic vs per-head blocks
// (the round-4 bottleneck: L2-miss BW ~2 TB/s on 278 MB of re-staging).
// Block = (group=bid&7 -> (b,kvh), qt=bid>>3 in [0,32) -> q rows [qt*64,qt*64+64)).
// Wave w: head = kvh*4 + (w&3), q-subrange qseg=(w>>2)*32, M/wave=32 (2 m-frags).
// Fixed-max base-2 softmax (Q pre-scaled by SCALE*log2e; scores bounded by 16.33).
// LDS = Ks 16K + VTs 16K + P slabs 32K = exactly 64 KB -> 1 block/CU.
__global__ __launch_bounds__(512, 2) void flash_attn(
    const bf16* __restrict__ Q, const bf16* __restrict__ Kb,
    const bf16* __restrict__ VT, const bf16* __restrict__ qkv,
    bf16* __restrict__ Aout) {
  __shared__ bf16 Ks[KT * 128];    // [key_row][chunk^(row&15)] 16B chunks
  __shared__ bf16 VTs[128 * KT];   // [d_row][chunk^(row&7)]
  __shared__ bf16 Ps[8 * 32 * 64]; // per-wave 32x64, chunk^(row&7) swizzle
  const int bid = blockIdx.x;
  const int group = bid & 7;       // (b,kvh): XCD-pin attempt; 1 MB K/V window
  const int b = group >> 2;
  const int kvh = group & 3;
  const int qt = 31 - (bid >> 3);  // long blocks first
  const int t = threadIdx.x, w = t >> 6, lane = t & 63;
  const int quad = lane >> 4, l16 = lane & 15;
  const int hh = w & 3, qseg = w >> 2;
  const int h = kvh * 4 + hh;
  const int qm0 = qt * 64;

  const bf16* Qb = Q + ((long)(b * NHEADS + h) * S_LEN + qm0 + qseg * 32) * HDIM;
  short8 qf[2][4];
#pragma unroll
  for (int mi = 0; mi < 2; mi++)
#pragma unroll
    for (int kc = 0; kc < 4; kc++)
      qf[mi][kc] = *(const short8*)(Qb + (mi * 16 + l16) * HDIM + kc * 32 + quad * 8);

  f32x4 oacc[2][8] = {};
  float lrun[2][4] = {};  // per-lane partial row sums

  const bf16* Kbase = Kb + (long)(b * NKVH + kvh) * S_LEN * HDIM;
  const bf16* VTbase = VT + (long)(b * NKVH + kvh) * HDIM * S_LEN;
  bf16* Pw = Ps + w * (32 * 64);

  const int nkt = qt + 1;
  for (int kt = 0; kt < nkt; kt++) {
    const int kn0 = kt * KT;
    __syncthreads();
#pragma unroll
    for (int i = 0; i < 2; i++) {
      int ci = i * 512 + t;
      int kr = ci >> 4;
      int kc8 = ((ci & 15) ^ (kr & 15)) * 8;
      async16(Kbase + (long)(kn0 + kr) * HDIM + kc8, Ks + ci * 8);
      int vr = ci >> 3;
      int vc8 = ((ci & 7) ^ (vr & 7)) * 8;
      async16(VTbase + (long)vr * S_LEN + kn0 + vc8, VTs + ci * 8);
    }
    __syncthreads();

    // S = Q @ K^T (swizzled reads: conflict-free)
    f32x4 sacc[2][4] = {};
#pragma unroll
    for (int kc = 0; kc < 4; kc++) {
      short8 bfr[4];
#pragma unroll
      for (int ni = 0; ni < 4; ni++)
        bfr[ni] = *(const short8*)(Ks + (ni * 16 + l16) * 128 + (((kc * 4 + quad) ^ l16) << 3));
#pragma unroll
      for (int ni = 0; ni < 4; ni++)
#pragma unroll
        for (int mi = 0; mi < 2; mi++)
          sacc[mi][ni] = mfma_bf16(qf[mi][kc], bfr[ni], sacc[mi][ni]);
    }

    // fixed-max softmax: p = exp2(s - 17); per-lane partial row sums
    const bool diag = (kt == qt);
#pragma unroll
    for (int mi = 0; mi < 2; mi++)
#pragma unroll
      for (int r = 0; r < 4; r++) {
        const int ql = qseg * 32 + mi * 16 + quad * 4 + r;  // local query in [0,64)
        if (diag) {
#pragma unroll
          for (int ni = 0; ni < 4; ni++)
            if (ni * 16 + l16 > ql) sacc[mi][ni][r] = NEG_INF;
        }
        float rsum = lrun[mi][r];
#pragma unroll
        for (int ni = 0; ni < 4; ni++) {
          float p = exp2f(sacc[mi][ni][r] - FIXED_M);
          sacc[mi][ni][r] = p;
          rsum += p;
        }
        lrun[mi][r] = rsum;
      }

    // P -> own swizzled LDS slab (stride 64, chunk ^ (row&7); no barrier needed)
#pragma unroll
    for (int mi = 0; mi < 2; mi++)
#pragma unroll
      for (int ni = 0; ni < 4; ni++)
#pragma unroll
        for (int r = 0; r < 4; r++) {
          const int row = mi * 16 + quad * 4 + r;
          Pw[row * 64 + (((ni * 2 + (l16 >> 3)) ^ (row & 7)) << 3) + (l16 & 7)] =
              __float2bfloat16(sacc[mi][ni][r]);
        }

    // O += P @ V
#pragma unroll
    for (int kc = 0; kc < 2; kc++) {
      short8 pf[2];
#pragma unroll
      for (int mi = 0; mi < 2; mi++) {
        const int row = mi * 16 + l16;
        pf[mi] = *(const short8*)(Pw + row * 64 + (((kc * 4 + quad) ^ (row & 7)) << 3));
      }
#pragma unroll
      for (int ni = 0; ni < 8; ni++) {
        short8 vf = *(const short8*)(VTs + (ni * 16 + l16) * 64 +
                                     (((kc * 4 + quad) ^ (l16 & 7)) << 3));
#pragma unroll
        for (int mi = 0; mi < 2; mi++)
          oacc[mi][ni] = mfma_bf16(pf[mi], vf, oacc[mi][ni]);
      }
    }
  }

  // epilogue: reduce row sums once, repack O via own P slab, gate, coalesced store
  float inv[2][4];
#pragma unroll
  for (int mi = 0; mi < 2; mi++)
#pragma unroll
    for (int r = 0; r < 4; r++) {
      float s = lrun[mi][r];
#pragma unroll
      for (int o = 1; o < 16; o <<= 1) s += __shfl_xor(s, o, 64);
      inv[mi][r] = 1.0f / s;
    }

#pragma unroll
  for (int h2 = 0; h2 < 2; h2++) {
    // write normalized O (cols h2*64..h2*64+63) into own slab, swizzled
#pragma unroll
    for (int mi = 0; mi < 2; mi++)
#pragma unroll
      for (int nj = 0; nj < 4; nj++)
#pragma unroll
        for (int r = 0; r < 4; r++) {
          const int row = mi * 16 + quad * 4 + r;
          Pw[row * 64 + (((nj * 2 + (l16 >> 3)) ^ (row & 7)) << 3) + (l16 & 7)] =
              __float2bfloat16(oacc[mi][h2 * 4 + nj][r] * inv[mi][r]);
        }
    // readback rows, apply sigmoid gate (16B loads), 16B coalesced stores
#pragma unroll
    for (int i = 0; i < 4; i++) {
      const int lrow = i * 8 + (lane >> 3);
      const int coff = (lane & 7) * 8;
      short8 o8 = *(const short8*)(Pw + lrow * 64 + ((((lane & 7) ^ (lrow & 7))) << 3));
      const long srow = qm0 + qseg * 32 + lrow;
      const bf16* gp = qkv + ((long)b * S_LEN + srow) * QKVN + h * 256 + 128 + h2 * 64 + coff;
      short8 g8 = *(const short8*)gp;
      short8 res;
#pragma unroll
      for (int e = 0; e < 8; e++) {
        float ov = bfbits_to_f(o8[e]);
        float gv = bfbits_to_f(g8[e]);
        res[e] = f_to_bfbits(ov / (1.0f + __expf(-gv)));
      }
      *(short8*)(Aout + ((long)b * S_LEN + srow) * 2048 + h * 128 + h2 * 64 + coff) = res;
    }
  }
}

extern "C" void kernel_launch(void* const* d_in, const int* in_sizes, int n_in,
                              void* d_out, int out_size, void* d_ws, size_t ws_size,
                              hipStream_t stream) {
  const float* hs = (const float*)d_in[0];
  const float* wq = (const float*)d_in[1];
  const float* wk = (const float*)d_in[2];
  const float* wv = (const float*)d_in[3];
  const float* wo = (const float*)d_in[4];
  const float* qnw = (const float*)d_in[5];
  const float* knw = (const float*)d_in[6];
  const float* rcos = (const float*)d_in[7];
  const float* rsin = (const float*)d_in[8];

  float* out = (float*)d_out;                 // (2,2048,2048)
  float* kcache = out + 8388608;              // (2,4,2048,128)
  float* vcache = out + 10485760;             // (2,4,2048,128)

  char* ws = (char*)d_ws;
  bf16* Xb    = (bf16*)(ws);                  // (4096,2048)
  bf16* WqkvT = (bf16*)(ws + 16777216L);      // (5120,2048)
  bf16* WoT   = (bf16*)(ws + 37748736L);      // (2048,2048)
  bf16* QKV   = (bf16*)(ws + 46137344L);      // (4096,5120)
  bf16* Qb    = (bf16*)(ws + 88080384L);      // (2,16,2048,128)
  bf16* Kbq   = (bf16*)(ws + 104857600L);     // (2,4,2048,128)
  bf16* VTb   = (bf16*)(ws + 109051904L);     // (2,4,128,2048)
  bf16* Aout  = (bf16*)(ws + 113246208L);     // (4096,2048)

  cast_kernel<<<8192, 256, 0, stream>>>(hs, Xb, 8388608);
  transpose_cast<<<dim3(128, 64, 1), dim3(32, 8), 0, stream>>>(wq, WqkvT, 2048, 4096, 0, 0);
  transpose_cast<<<dim3(16, 64, 1), dim3(32, 8), 0, stream>>>(wk, WqkvT + 4096L * 2048, 2048, 512, 0, 0);
  transpose_cast<<<dim3(16, 64, 1), dim3(32, 8), 0, stream>>>(wv, WqkvT + 4608L * 2048, 2048, 512, 0, 0);
  transpose_cast<<<dim3(64, 64, 1), dim3(32, 8), 0, stream>>>(wo, WoT, 2048, 2048, 0, 0);

  gemm_bt<bf16><<<dim3(32, 40), 256, 0, stream>>>(Xb, WqkvT, QKV, 2048, 5120);

  qkv_post<<<4096, 256, 0, stream>>>(QKV, qnw, knw, rcos, rsin, Qb, Kbq, kcache, vcache);

  // V^T (per (b,kv): (2048,128) f32 -> (128,2048) bf16)
  transpose_cast<<<dim3(4, 64, 8), dim3(32, 8), 0, stream>>>(vcache, VTb, 2048, 128,
                                                             2048L * 128, 2048L * 128);

  flash_attn<<<256, 512, 0, stream>>>(Qb, Kbq, VTb, QKV, Aout);

  gemm_bt<float><<<dim3(32, 16), 256, 0, stream>>>(Aout, WoT, out, 2048, 2048);
}

// Round 6
// 409.331 us; speedup vs baseline: 1.7511x; 1.0917x over previous
//
#include <hip/hip_runtime.h>
#include <hip/hip_bf16.h>

typedef __hip_bfloat16 bf16;
typedef short short8 __attribute__((ext_vector_type(8)));
typedef float f32x4 __attribute__((ext_vector_type(4)));

#define S_LEN 2048
#define NHEADS 16
#define NKVH 4
#define HDIM 128
#define QKVN 5120
#define EPS_F 1e-6f
#define NEG_INF -1e30f
// SCALE * log2(e): attention scores computed in base-2 domain
#define QSCALE 0.12751744f
// |score*log2e| <= sqrt(128)*sqrt(128)*SCALE*log2e = 16.33 -> fixed softmax max
#define FIXED_M 17.0f

#define KT 64

__device__ __forceinline__ void async16(const bf16* g, bf16* l) {
  __builtin_amdgcn_global_load_lds(
      (const __attribute__((address_space(1))) void*)g,
      (__attribute__((address_space(3))) void*)l, 16, 0, 0);
}

__device__ __forceinline__ f32x4 mfma_bf16(short8 a, short8 b, f32x4 c) {
  return __builtin_amdgcn_mfma_f32_16x16x32_bf16(a, b, c, 0, 0, 0);
}

__device__ __forceinline__ float bfbits_to_f(short s) {
  unsigned u = ((unsigned)(unsigned short)s) << 16;
  return __uint_as_float(u);
}
__device__ __forceinline__ short f_to_bfbits(float f) {
  __hip_bfloat16 h = __float2bfloat16(f);
  return *reinterpret_cast<short*>(&h);
}

__device__ __forceinline__ void store_c(float* p, float v) { *p = v; }
__device__ __forceinline__ void store_c(bf16* p, float v) { *p = __float2bfloat16(v); }

// ---------------- cast f32 -> bf16 ----------------
__global__ __launch_bounds__(256) void cast_kernel(const float* __restrict__ in,
                                                   bf16* __restrict__ out, int n) {
  int i = (blockIdx.x * 256 + threadIdx.x) * 4;
  if (i + 3 < n) {
    float4 v = *(const float4*)(in + i);
    __hip_bfloat162 p0, p1;
    p0.x = __float2bfloat16(v.x); p0.y = __float2bfloat16(v.y);
    p1.x = __float2bfloat16(v.z); p1.y = __float2bfloat16(v.w);
    *(__hip_bfloat162*)(out + i) = p0;
    *(__hip_bfloat162*)(out + i + 2) = p1;
  }
}

// ---------------- tiled transpose + cast: in (H,N) f32 -> out (N,H) bf16 ----------------
__global__ __launch_bounds__(256) void transpose_cast(const float* __restrict__ in,
                                                      bf16* __restrict__ out, int H, int N,
                                                      long inBS, long outBS) {
  __shared__ float tile[32][33];
  const float* ip = in + (long)blockIdx.z * inBS;
  bf16* op = out + (long)blockIdx.z * outBS;
  int n0 = blockIdx.x * 32, h0 = blockIdx.y * 32;
  int tx = threadIdx.x, ty = threadIdx.y;
#pragma unroll
  for (int i = 0; i < 4; i++)
    tile[ty + i * 8][tx] = ip[(long)(h0 + ty + i * 8) * N + n0 + tx];
  __syncthreads();
#pragma unroll
  for (int i = 0; i < 4; i++)
    op[(long)(n0 + ty + i * 8) * H + h0 + tx] = __float2bfloat16(tile[tx][ty + i * 8]);
}

// ---------------- bt-form bf16 GEMM, BK=64: C[m][n] = sum_k A[m][k]*BT[n][k] ----------------
// vs m97 (BK=32): half the barrier-pairs (32 MFMA per staging round), LDS 32 KB.
// Row stride is 64 elems (128 B = all 32 banks), so tiles use the flash-verified
// XOR chunk swizzle (16B chunk c of row r lives at slot c^(r&7)) -> conflict-free
// ds_read_b128; staging permutes the GLOBAL source chunk so global_load_lds
// destinations stay lane-contiguous.
template <typename CT>
__global__ __launch_bounds__(256) void gemm_bt(const bf16* __restrict__ A,
                                               const bf16* __restrict__ BT,
                                               CT* __restrict__ C, int K, int ldc) {
  __shared__ bf16 As[128 * 64];
  __shared__ bf16 Bs[128 * 64];
  const int t = threadIdx.x;
  const int wid = t >> 6, lane = t & 63;
  const int quad = lane >> 4, l16 = lane & 15;
  const int wm = (wid & 1) * 64, wn = (wid >> 1) * 64;
  const long m0 = (long)blockIdx.x * 128;
  const long n0 = (long)blockIdx.y * 128;

  // staging map: chunk index ci = i*256+t (i=0..3) -> row=ci>>3, swizzled col
  const bf16* Ag[4];
  const bf16* Bg[4];
#pragma unroll
  for (int i = 0; i < 4; i++) {
    const int ci = i * 256 + t;
    const int row = ci >> 3;
    const int col = ((ci & 7) ^ (row & 7)) * 8;
    Ag[i] = A + (m0 + row) * K + col;
    Bg[i] = BT + (n0 + row) * K + col;
  }

  f32x4 acc[4][4] = {};

  for (int k0 = 0; k0 < K; k0 += 64) {
    __syncthreads();
#pragma unroll
    for (int i = 0; i < 4; i++) {
      async16(Ag[i] + k0, As + (i * 256 + t) * 8);
      async16(Bg[i] + k0, Bs + (i * 256 + t) * 8);
    }
    __syncthreads();
#pragma unroll
    for (int kc = 0; kc < 2; kc++) {
      short8 af[4], bfr[4];
#pragma unroll
      for (int i = 0; i < 4; i++) {
        af[i] = *(const short8*)(As + (wm + i * 16 + l16) * 64 +
                                 (((kc * 4 + quad) ^ (l16 & 7)) << 3));
        bfr[i] = *(const short8*)(Bs + (wn + i * 16 + l16) * 64 +
                                  (((kc * 4 + quad) ^ (l16 & 7)) << 3));
      }
#pragma unroll
      for (int mi = 0; mi < 4; mi++)
#pragma unroll
        for (int ni = 0; ni < 4; ni++)
          acc[mi][ni] = mfma_bf16(af[mi], bfr[ni], acc[mi][ni]);
    }
  }

#pragma unroll
  for (int mi = 0; mi < 4; mi++)
#pragma unroll
    for (int ni = 0; ni < 4; ni++)
#pragma unroll
      for (int r = 0; r < 4; r++) {
        long row = m0 + wm + mi * 16 + quad * 4 + r;
        long col = n0 + wn + ni * 16 + l16;
        store_c(C + row * ldc + col, acc[mi][ni][r]);
      }
}

// ---------------- QKV post: rmsnorm + rope + cache writes ----------------
__global__ __launch_bounds__(256) void qkv_post(
    const bf16* __restrict__ qkv, const float* __restrict__ qw,
    const float* __restrict__ kw, const float* __restrict__ rcos,
    const float* __restrict__ rsin, bf16* __restrict__ Q, bf16* __restrict__ Kb,
    float* __restrict__ kcache, float* __restrict__ vcache) {
  const int bs = blockIdx.x;
  const int b = bs >> 11;
  const int s = bs & 2047;
  const int t = threadIdx.x, wid = t >> 6, lane = t & 63;
  const int d0 = lane * 2;
  const bf16* row = qkv + (long)bs * QKVN;
  float cs = 0.f, sn = 0.f;
  if (lane < 16) {
    cs = rcos[s * 16 + lane];
    sn = rsin[s * 16 + lane];
  }
  for (int seg = wid; seg < 24; seg += 4) {
    if (seg < 16) {
      int h = seg;
      __hip_bfloat162 xr = *(const __hip_bfloat162*)(row + h * 256 + d0);
      float x0 = __bfloat162float(xr.x), x1 = __bfloat162float(xr.y);
      float ss = x0 * x0 + x1 * x1;
      for (int o = 32; o; o >>= 1) ss += __shfl_xor(ss, o, 64);
      float rn = rsqrtf(ss * (1.0f / 128.0f) + EPS_F);
      float y0 = x0 * rn * (1.0f + qw[d0]);
      float y1 = x1 * rn * (1.0f + qw[d0 + 1]);
      if (lane < 16) {
        float t0 = y0 * cs - y1 * sn;
        y1 = y1 * cs + y0 * sn;
        y0 = t0;
      }
      y0 *= QSCALE;  // fold softmax scale * log2(e) into Q
      y1 *= QSCALE;
      __hip_bfloat162 o2;
      o2.x = __float2bfloat16(y0); o2.y = __float2bfloat16(y1);
      *(__hip_bfloat162*)(Q + ((long)(b * NHEADS + h) * S_LEN + s) * HDIM + d0) = o2;
    } else if (seg < 20) {
      int j = seg - 16;
      __hip_bfloat162 xr = *(const __hip_bfloat162*)(row + 4096 + j * 128 + d0);
      float x0 = __bfloat162float(xr.x), x1 = __bfloat162float(xr.y);
      float ss = x0 * x0 + x1 * x1;
      for (int o = 32; o; o >>= 1) ss += __shfl_xor(ss, o, 64);
      float rn = rsqrtf(ss * (1.0f / 128.0f) + EPS_F);
      float y0 = x0 * rn * (1.0f + kw[d0]);
      float y1 = x1 * rn * (1.0f + kw[d0 + 1]);
      if (lane < 16) {
        float t0 = y0 * cs - y1 * sn;
        y1 = y1 * cs + y0 * sn;
        y0 = t0;
      }
      long idx = ((long)(b * NKVH + j) * S_LEN + s) * HDIM + d0;
      __hip_bfloat162 o2;
      o2.x = __float2bfloat16(y0); o2.y = __float2bfloat16(y1);
      *(__hip_bfloat162*)(Kb + idx) = o2;
      float2 f2; f2.x = y0; f2.y = y1;
      *(float2*)(kcache + idx) = f2;
    } else {
      int j = seg - 20;
      __hip_bfloat162 xr = *(const __hip_bfloat162*)(row + 4608 + j * 128 + d0);
      float2 f2;
      f2.x = __bfloat162float(xr.x); f2.y = __bfloat162float(xr.y);
      *(float2*)(vcache + ((long)(b * NKVH + j) * S_LEN + s) * HDIM + d0) = f2;
    }
  }
}

// ---------------- flash attention (causal, GQA) + fused sigmoid gate ----------------
// GQA head-sharing block: 512 threads = 8 waves = 4 heads x 2 q-halves, all sharing
// ONE staged K/V tile (KT=64) -> halves K/V staging traffic vs per-head blocks.
// Block = (group=bid&7 -> (b,kvh), qt=bid>>3 in [0,32) -> q rows [qt*64,qt*64+64)).
// Wave w: head = kvh*4 + (w&3), q-subrange qseg=(w>>2)*32, M/wave=32 (2 m-frags).
// Fixed-max base-2 softmax (Q pre-scaled by SCALE*log2e; scores bounded by 16.33).
// LDS = Ks 16K + VTs 16K + P slabs 32K = exactly 64 KB -> 1 block/CU.
__global__ __launch_bounds__(512, 2) void flash_attn(
    const bf16* __restrict__ Q, const bf16* __restrict__ Kb,
    const bf16* __restrict__ VT, const bf16* __restrict__ qkv,
    bf16* __restrict__ Aout) {
  __shared__ bf16 Ks[KT * 128];    // [key_row][chunk^(row&15)] 16B chunks
  __shared__ bf16 VTs[128 * KT];   // [d_row][chunk^(row&7)]
  __shared__ bf16 Ps[8 * 32 * 64]; // per-wave 32x64, chunk^(row&7) swizzle
  const int bid = blockIdx.x;
  const int group = bid & 7;       // (b,kvh): XCD-pin attempt; 1 MB K/V window
  const int b = group >> 2;
  const int kvh = group & 3;
  const int qt = 31 - (bid >> 3);  // long blocks first
  const int t = threadIdx.x, w = t >> 6, lane = t & 63;
  const int quad = lane >> 4, l16 = lane & 15;
  const int hh = w & 3, qseg = w >> 2;
  const int h = kvh * 4 + hh;
  const int qm0 = qt * 64;

  const bf16* Qb = Q + ((long)(b * NHEADS + h) * S_LEN + qm0 + qseg * 32) * HDIM;
  short8 qf[2][4];
#pragma unroll
  for (int mi = 0; mi < 2; mi++)
#pragma unroll
    for (int kc = 0; kc < 4; kc++)
      qf[mi][kc] = *(const short8*)(Qb + (mi * 16 + l16) * HDIM + kc * 32 + quad * 8);

  f32x4 oacc[2][8] = {};
  float lrun[2][4] = {};  // per-lane partial row sums

  const bf16* Kbase = Kb + (long)(b * NKVH + kvh) * S_LEN * HDIM;
  const bf16* VTbase = VT + (long)(b * NKVH + kvh) * HDIM * S_LEN;
  bf16* Pw = Ps + w * (32 * 64);

  const int nkt = qt + 1;
  for (int kt = 0; kt < nkt; kt++) {
    const int kn0 = kt * KT;
    __syncthreads();
#pragma unroll
    for (int i = 0; i < 2; i++) {
      int ci = i * 512 + t;
      int kr = ci >> 4;
      int kc8 = ((ci & 15) ^ (kr & 15)) * 8;
      async16(Kbase + (long)(kn0 + kr) * HDIM + kc8, Ks + ci * 8);
      int vr = ci >> 3;
      int vc8 = ((ci & 7) ^ (vr & 7)) * 8;
      async16(VTbase + (long)vr * S_LEN + kn0 + vc8, VTs + ci * 8);
    }
    __syncthreads();

    // S = Q @ K^T (swizzled reads: conflict-free)
    f32x4 sacc[2][4] = {};
#pragma unroll
    for (int kc = 0; kc < 4; kc++) {
      short8 bfr[4];
#pragma unroll
      for (int ni = 0; ni < 4; ni++)
        bfr[ni] = *(const short8*)(Ks + (ni * 16 + l16) * 128 + (((kc * 4 + quad) ^ l16) << 3));
#pragma unroll
      for (int ni = 0; ni < 4; ni++)
#pragma unroll
        for (int mi = 0; mi < 2; mi++)
          sacc[mi][ni] = mfma_bf16(qf[mi][kc], bfr[ni], sacc[mi][ni]);
    }

    // fixed-max softmax: p = exp2(s - 17); per-lane partial row sums
    const bool diag = (kt == qt);
#pragma unroll
    for (int mi = 0; mi < 2; mi++)
#pragma unroll
      for (int r = 0; r < 4; r++) {
        const int ql = qseg * 32 + mi * 16 + quad * 4 + r;  // local query in [0,64)
        if (diag) {
#pragma unroll
          for (int ni = 0; ni < 4; ni++)
            if (ni * 16 + l16 > ql) sacc[mi][ni][r] = NEG_INF;
        }
        float rsum = lrun[mi][r];
#pragma unroll
        for (int ni = 0; ni < 4; ni++) {
          float p = exp2f(sacc[mi][ni][r] - FIXED_M);
          sacc[mi][ni][r] = p;
          rsum += p;
        }
        lrun[mi][r] = rsum;
      }

    // P -> own swizzled LDS slab (stride 64, chunk ^ (row&7); no barrier needed)
#pragma unroll
    for (int mi = 0; mi < 2; mi++)
#pragma unroll
      for (int ni = 0; ni < 4; ni++)
#pragma unroll
        for (int r = 0; r < 4; r++) {
          const int row = mi * 16 + quad * 4 + r;
          Pw[row * 64 + (((ni * 2 + (l16 >> 3)) ^ (row & 7)) << 3) + (l16 & 7)] =
              __float2bfloat16(sacc[mi][ni][r]);
        }

    // O += P @ V
#pragma unroll
    for (int kc = 0; kc < 2; kc++) {
      short8 pf[2];
#pragma unroll
      for (int mi = 0; mi < 2; mi++) {
        const int row = mi * 16 + l16;
        pf[mi] = *(const short8*)(Pw + row * 64 + (((kc * 4 + quad) ^ (row & 7)) << 3));
      }
#pragma unroll
      for (int ni = 0; ni < 8; ni++) {
        short8 vf = *(const short8*)(VTs + (ni * 16 + l16) * 64 +
                                     (((kc * 4 + quad) ^ (l16 & 7)) << 3));
#pragma unroll
        for (int mi = 0; mi < 2; mi++)
          oacc[mi][ni] = mfma_bf16(pf[mi], vf, oacc[mi][ni]);
      }
    }
  }

  // epilogue: reduce row sums once, repack O via own P slab, gate, coalesced store
  float inv[2][4];
#pragma unroll
  for (int mi = 0; mi < 2; mi++)
#pragma unroll
    for (int r = 0; r < 4; r++) {
      float s = lrun[mi][r];
#pragma unroll
      for (int o = 1; o < 16; o <<= 1) s += __shfl_xor(s, o, 64);
      inv[mi][r] = 1.0f / s;
    }

#pragma unroll
  for (int h2 = 0; h2 < 2; h2++) {
    // write normalized O (cols h2*64..h2*64+63) into own slab, swizzled
#pragma unroll
    for (int mi = 0; mi < 2; mi++)
#pragma unroll
      for (int nj = 0; nj < 4; nj++)
#pragma unroll
        for (int r = 0; r < 4; r++) {
          const int row = mi * 16 + quad * 4 + r;
          Pw[row * 64 + (((nj * 2 + (l16 >> 3)) ^ (row & 7)) << 3) + (l16 & 7)] =
              __float2bfloat16(oacc[mi][h2 * 4 + nj][r] * inv[mi][r]);
        }
    // readback rows, apply sigmoid gate (16B loads), 16B coalesced stores
#pragma unroll
    for (int i = 0; i < 4; i++) {
      const int lrow = i * 8 + (lane >> 3);
      const int coff = (lane & 7) * 8;
      short8 o8 = *(const short8*)(Pw + lrow * 64 + ((((lane & 7) ^ (lrow & 7))) << 3));
      const long srow = qm0 + qseg * 32 + lrow;
      const bf16* gp = qkv + ((long)b * S_LEN + srow) * QKVN + h * 256 + 128 + h2 * 64 + coff;
      short8 g8 = *(const short8*)gp;
      short8 res;
#pragma unroll
      for (int e = 0; e < 8; e++) {
        float ov = bfbits_to_f(o8[e]);
        float gv = bfbits_to_f(g8[e]);
        res[e] = f_to_bfbits(ov / (1.0f + __expf(-gv)));
      }
      *(short8*)(Aout + ((long)b * S_LEN + srow) * 2048 + h * 128 + h2 * 64 + coff) = res;
    }
  }
}

extern "C" void kernel_launch(void* const* d_in, const int* in_sizes, int n_in,
                              void* d_out, int out_size, void* d_ws, size_t ws_size,
                              hipStream_t stream) {
  const float* hs = (const float*)d_in[0];
  const float* wq = (const float*)d_in[1];
  const float* wk = (const float*)d_in[2];
  const float* wv = (const float*)d_in[3];
  const float* wo = (const float*)d_in[4];
  const float* qnw = (const float*)d_in[5];
  const float* knw = (const float*)d_in[6];
  const float* rcos = (const float*)d_in[7];
  const float* rsin = (const float*)d_in[8];

  float* out = (float*)d_out;                 // (2,2048,2048)
  float* kcache = out + 8388608;              // (2,4,2048,128)
  float* vcache = out + 10485760;             // (2,4,2048,128)

  char* ws = (char*)d_ws;
  bf16* Xb    = (bf16*)(ws);                  // (4096,2048)
  bf16* WqkvT = (bf16*)(ws + 16777216L);      // (5120,2048)
  bf16* WoT   = (bf16*)(ws + 37748736L);      // (2048,2048)
  bf16* QKV   = (bf16*)(ws + 46137344L);      // (4096,5120)
  bf16* Qb    = (bf16*)(ws + 88080384L);      // (2,16,2048,128)
  bf16* Kbq   = (bf16*)(ws + 104857600L);     // (2,4,2048,128)
  bf16* VTb   = (bf16*)(ws + 109051904L);     // (2,4,128,2048)
  bf16* Aout  = (bf16*)(ws + 113246208L);     // (4096,2048)

  cast_kernel<<<8192, 256, 0, stream>>>(hs, Xb, 8388608);
  transpose_cast<<<dim3(128, 64, 1), dim3(32, 8), 0, stream>>>(wq, WqkvT, 2048, 4096, 0, 0);
  transpose_cast<<<dim3(16, 64, 1), dim3(32, 8), 0, stream>>>(wk, WqkvT + 4096L * 2048, 2048, 512, 0, 0);
  transpose_cast<<<dim3(16, 64, 1), dim3(32, 8), 0, stream>>>(wv, WqkvT + 4608L * 2048, 2048, 512, 0, 0);
  transpose_cast<<<dim3(64, 64, 1), dim3(32, 8), 0, stream>>>(wo, WoT, 2048, 2048, 0, 0);

  gemm_bt<bf16><<<dim3(32, 40), 256, 0, stream>>>(Xb, WqkvT, QKV, 2048, 5120);

  qkv_post<<<4096, 256, 0, stream>>>(QKV, qnw, knw, rcos, rsin, Qb, Kbq, kcache, vcache);

  // V^T (per (b,kv): (2048,128) f32 -> (128,2048) bf16)
  transpose_cast<<<dim3(4, 64, 8), dim3(32, 8), 0, stream>>>(vcache, VTb, 2048, 128,
                                                             2048L * 128, 2048L * 128);

  flash_attn<<<256, 512, 0, stream>>>(Qb, Kbq, VTb, QKV, Aout);

  gemm_bt<float><<<dim3(32, 16), 256, 0, stream>>>(Aout, WoT, out, 2048, 2048);
}